// Round 4
// baseline (298.739 us; speedup 1.0000x reference)
//
#include <hip/hip_runtime.h>
#include <math.h>

// Problem constants
#define M_B   128      // batch
#define N_C   1024     // codes
#define K_D   32000    // feature dim (8*250*16)
#define NTILE 32       // codes per block
#define NNT   (N_C / NTILE)   // 32 n-tiles
#define KCHUNK 1280    // K per block
#define NKC   (K_D / KCHUNK)  // 25 k-chunks -> grid 32x25 = 800 blocks
#define KSTEP 64       // bf16 elems staged in LDS per step (20 steps/block)
#define NSTAGE (KCHUNK / KSTEP)  // 20
#define LDSK  (KSTEP + 8)   // 144B row stride, 16B-aligned rows
#define TOPK  5
#define TEMP  0.1f

typedef short bf16x8 __attribute__((ext_vector_type(8)));  // 8 bf16 (4 VGPRs)
typedef float f32x4  __attribute__((ext_vector_type(4)));

// ws layout (float offsets) — tiny now; partials live in d_out quant region
#define WS_TOPI 0     // [128*5] int
#define WS_TOPW 640   // [128*5] float

// Barrier WITHOUT vmcnt drain: only LDS (lgkm) visibility is needed for the
// double-buffer handoff. All global prefetches are issued BEFORE this point
// in source order and consumed a full step later (r1/r3 post-mortem).
#define LDS_BARRIER()                                        \
  do {                                                       \
    asm volatile("s_waitcnt lgkmcnt(0)" ::: "memory");       \
    __builtin_amdgcn_s_barrier();                            \
    __builtin_amdgcn_sched_barrier(0);                       \
  } while (0)

// ---------------------------------------------------------------------------
// fp32x8 -> bf16x8 hi plane + lo plane (exact split: x = hi + lo + ~2^-18 rel)
// ---------------------------------------------------------------------------
__device__ inline void cvt8(const float4 p0, const float4 p1, uint4& hi,
                            uint4& lo) {
  const unsigned int u0 = __float_as_uint(p0.x), u1 = __float_as_uint(p0.y);
  const unsigned int u2 = __float_as_uint(p0.z), u3 = __float_as_uint(p0.w);
  const unsigned int u4 = __float_as_uint(p1.x), u5 = __float_as_uint(p1.y);
  const unsigned int u6 = __float_as_uint(p1.z), u7 = __float_as_uint(p1.w);
  hi.x = (u0 >> 16) | (u1 & 0xFFFF0000u);
  hi.y = (u2 >> 16) | (u3 & 0xFFFF0000u);
  hi.z = (u4 >> 16) | (u5 & 0xFFFF0000u);
  hi.w = (u6 >> 16) | (u7 & 0xFFFF0000u);
  const float l0 = p0.x - __uint_as_float(u0 & 0xFFFF0000u);
  const float l1 = p0.y - __uint_as_float(u1 & 0xFFFF0000u);
  const float l2 = p0.z - __uint_as_float(u2 & 0xFFFF0000u);
  const float l3 = p0.w - __uint_as_float(u3 & 0xFFFF0000u);
  const float l4 = p1.x - __uint_as_float(u4 & 0xFFFF0000u);
  const float l5 = p1.y - __uint_as_float(u5 & 0xFFFF0000u);
  const float l6 = p1.z - __uint_as_float(u6 & 0xFFFF0000u);
  const float l7 = p1.w - __uint_as_float(u7 & 0xFFFF0000u);
  lo.x = (__float_as_uint(l0) >> 16) | (__float_as_uint(l1) & 0xFFFF0000u);
  lo.y = (__float_as_uint(l2) >> 16) | (__float_as_uint(l3) & 0xFFFF0000u);
  lo.z = (__float_as_uint(l4) >> 16) | (__float_as_uint(l5) & 0xFFFF0000u);
  lo.w = (__float_as_uint(l6) >> 16) | (__float_as_uint(l7) & 0xFFFF0000u);
}

__device__ inline float sq8(const float4 p0, const float4 p1) {
  return p0.x * p0.x + p0.y * p0.y + p0.z * p0.z + p0.w * p0.w +
         p1.x * p1.x + p1.y * p1.y + p1.z * p1.z + p1.w * p1.w;
}

// ---------------------------------------------------------------------------
// Split-bf16 MFMA distance GEMM v5 — atomic-free split-K.
//  - block (nt,kc) computes partial[kc,nt][b=0..127][col=0..31]
//      = cn_chunk[col] - 2 * (A_chunk . B_chunk)      (plain stores, no RMW)
//  - A cvt in-loop from fp32 latent (r1-proven: latent stays L3-hot, FETCH
//    = codebook only). Per step, source order:
//      cvt A(s) -> issue A(s+1) -> MFMA(LDS[p]) -> cvt+write B(s+1)
//      -> issue B(s+2) -> lgkm-only barrier
//    so every global load is issued pre-barrier and consumed a step later;
//    compiler emits counted vmcnt (2/8), never a drain.
//  - usage copy rides in block (0,0): gemm precedes finalize's atomics.
// ---------------------------------------------------------------------------
__global__ __launch_bounds__(256, 4) void gemm_dist(
    const float* __restrict__ latent, const float* __restrict__ codebook,
    const float* __restrict__ usage_in, float* __restrict__ usage_out,
    float* __restrict__ partial) {
  __shared__ alignas(16) unsigned short Bh[2][NTILE][LDSK];
  __shared__ alignas(16) unsigned short Bl[2][NTILE][LDSK];
  __shared__ float cnl[NTILE];

  const int tid = threadIdx.x;
  const int nt  = blockIdx.x;   // 0..31 N tile
  const int kc  = blockIdx.y;   // 0..24 K chunk

  if (nt == 0 && kc == 0) {  // usage copy (kernel order gemm -> finalize)
#pragma unroll
    for (int j = 0; j < 4; ++j)
      usage_out[tid + j * 256] = usage_in[tid + j * 256];
  }

  const int wave = tid >> 6;     // 0..3: M rows [32w, 32w+32)
  const int lane = tid & 63;
  const int lrow = lane & 15;    // MFMA fragment row/col index
  const int quad = lane >> 4;    // MFMA k-quad

  const int brow = tid >> 3;       // staging: B row 0..31
  const int bcol = (tid & 7) * 8;  // 8 k-elems (1 float4-pair) per thread

  f32x4 acc[2][2];
#pragma unroll
  for (int mt = 0; mt < 2; ++mt)
#pragma unroll
    for (int n = 0; n < 2; ++n) {
      acc[mt][n][0] = 0.f; acc[mt][n][1] = 0.f;
      acc[mt][n][2] = 0.f; acc[mt][n][3] = 0.f;
    }
  float csq = 0.f;

  const int kbase = kc * KCHUNK;
  const float* browp = codebook + (size_t)(nt * NTILE + brow) * K_D;

  // ---- prologue: stage B(0) into LDS[0] (one-time exposed latency) ----
  {
    const float4 p0 = *reinterpret_cast<const float4*>(browp + kbase + bcol);
    const float4 p1 =
        *reinterpret_cast<const float4*>(browp + kbase + bcol + 4);
    uint4 hi, lo;
    cvt8(p0, p1, hi, lo);
    *reinterpret_cast<uint4*>(&Bh[0][brow][bcol]) = hi;
    *reinterpret_cast<uint4*>(&Bl[0][brow][bcol]) = lo;
    csq += sq8(p0, p1);
  }
  // ---- issue A(0) ----
  float4 ap[2][2][2];  // [mt][kh][half]
#pragma unroll
  for (int mt = 0; mt < 2; ++mt) {
    const float* arow =
        latent + (size_t)(wave * 32 + mt * 16 + lrow) * K_D + kbase + quad * 8;
#pragma unroll
    for (int kh = 0; kh < 2; ++kh) {
      ap[mt][kh][0] = *reinterpret_cast<const float4*>(arow + kh * 32);
      ap[mt][kh][1] = *reinterpret_cast<const float4*>(arow + kh * 32 + 4);
    }
  }
  // ---- issue B(1) ----
  float4 bpA[2], bpB[2];
  bpA[0] = *reinterpret_cast<const float4*>(browp + kbase + KSTEP + bcol);
  bpA[1] = *reinterpret_cast<const float4*>(browp + kbase + KSTEP + bcol + 4);
  LDS_BARRIER();  // LDS[0] visible; A(0)/B(1) stay in flight (lgkm-only)

#define HALF_STEP(P, S, BCUR, BNXT)                                           \
  {                                                                           \
    /* 1. cvt A(S): waits vmcnt(2) (keeps B(S+1) in flight) */                \
    bf16x8 ah[2][2], al[2][2];                                                \
    _Pragma("unroll") for (int mt = 0; mt < 2; ++mt) {                        \
      _Pragma("unroll") for (int kh = 0; kh < 2; ++kh) {                      \
        uint4 hi, lo;                                                         \
        cvt8(ap[mt][kh][0], ap[mt][kh][1], hi, lo);                           \
        ah[mt][kh] = *reinterpret_cast<bf16x8*>(&hi);                         \
        al[mt][kh] = *reinterpret_cast<bf16x8*>(&lo);                         \
      }                                                                       \
    }                                                                         \
    /* 2. issue A(S+1) (clamped reload at tail; WAR-safe: cvt issued first)*/ \
    {                                                                         \
      const int ks = kbase + ((S) + 1 < NSTAGE ? (S) + 1 : (S)) * KSTEP;      \
      _Pragma("unroll") for (int mt = 0; mt < 2; ++mt) {                      \
        const float* arow = latent +                                          \
            (size_t)(wave * 32 + mt * 16 + lrow) * K_D + ks + quad * 8;       \
        _Pragma("unroll") for (int kh = 0; kh < 2; ++kh) {                    \
          ap[mt][kh][0] = *reinterpret_cast<const float4*>(arow + kh * 32);   \
          ap[mt][kh][1] =                                                     \
              *reinterpret_cast<const float4*>(arow + kh * 32 + 4);           \
        }                                                                     \
      }                                                                       \
    }                                                                         \
    /* 3. MFMA on LDS[P] */                                                   \
    _Pragma("unroll") for (int kh = 0; kh < 2; ++kh) {                        \
      const int kf = kh * 32 + quad * 8;                                      \
      _Pragma("unroll") for (int n = 0; n < 2; ++n) {                         \
        const bf16x8 bh =                                                     \
            *reinterpret_cast<const bf16x8*>(&Bh[P][n * 16 + lrow][kf]);      \
        const bf16x8 bl =                                                     \
            *reinterpret_cast<const bf16x8*>(&Bl[P][n * 16 + lrow][kf]);      \
        _Pragma("unroll") for (int mt = 0; mt < 2; ++mt) {                    \
          acc[mt][n] = __builtin_amdgcn_mfma_f32_16x16x32_bf16(               \
              ah[mt][kh], bh, acc[mt][n], 0, 0, 0);                           \
          acc[mt][n] = __builtin_amdgcn_mfma_f32_16x16x32_bf16(               \
              ah[mt][kh], bl, acc[mt][n], 0, 0, 0);                           \
          acc[mt][n] = __builtin_amdgcn_mfma_f32_16x16x32_bf16(               \
              al[mt][kh], bh, acc[mt][n], 0, 0, 0);                           \
        }                                                                     \
      }                                                                       \
    }                                                                         \
    /* 4. cvt+write B(S+1) (loaded a full step ago): waits vmcnt(8) */        \
    if ((S) + 1 < NSTAGE) {                                                   \
      uint4 hi, lo;                                                           \
      cvt8(BCUR[0], BCUR[1], hi, lo);                                         \
      *reinterpret_cast<uint4*>(&Bh[(P) ^ 1][brow][bcol]) = hi;               \
      *reinterpret_cast<uint4*>(&Bl[(P) ^ 1][brow][bcol]) = lo;               \
      csq += sq8(BCUR[0], BCUR[1]);                                           \
    }                                                                         \
    /* 5. issue B(S+2) (clamped; dual-buffer regs so issue is early) */       \
    {                                                                         \
      const int kn =                                                          \
          kbase + ((S) + 2 < NSTAGE ? (S) + 2 : NSTAGE - 1) * KSTEP + bcol;   \
      BNXT[0] = *reinterpret_cast<const float4*>(browp + kn);                 \
      BNXT[1] = *reinterpret_cast<const float4*>(browp + kn + 4);             \
    }                                                                         \
    LDS_BARRIER();                                                            \
  }

  for (int it = 0; it < NSTAGE / 2; ++it) {
    const int s0 = it * 2;
    HALF_STEP(0, s0, bpA, bpB)
    HALF_STEP(1, s0 + 1, bpB, bpA)
  }
#undef HALF_STEP

  // ---- codebook chunk norms: reduce 8 staging threads per row ----
  csq += __shfl_down(csq, 4, 8);
  csq += __shfl_down(csq, 2, 8);
  csq += __shfl_down(csq, 1, 8);
  if ((tid & 7) == 0) cnl[brow] = csq;
  __syncthreads();  // epilogue: full sync fine (loop done)

  // ---- non-atomic partial store: cn_chunk - 2*cross_chunk ----
  // C/D layout col=lane&15, row=quad*4+reg (m89)
  float* pbase = partial + (size_t)(kc * NNT + nt) * (M_B * NTILE);
#pragma unroll
  for (int mt = 0; mt < 2; ++mt) {
    const int r0 = wave * 32 + mt * 16 + quad * 4;
#pragma unroll
    for (int n = 0; n < 2; ++n) {
      const int col = n * 16 + lrow;
      const float cn = cnl[col];
#pragma unroll
      for (int r = 0; r < 4; ++r)
        pbase[(r0 + r) * NTILE + col] = cn - 2.f * acc[mt][n][r];
    }
  }
}

// ---------------------------------------------------------------------------
// Per-latent finalize: ln from latent + partial-sum -> d2 -> top-5 (lowest-
// index tie-break) -> softmax -> outputs + usage scatter + ws stash.
// ---------------------------------------------------------------------------
__global__ __launch_bounds__(256) void finalize(
    const float* __restrict__ latent, const float* __restrict__ partial,
    float* __restrict__ out_idx, float* __restrict__ out_dist,
    float* __restrict__ out_usage, int* __restrict__ topidx,
    float* __restrict__ topw) {
  const int b = blockIdx.x;
  const int tid = threadIdx.x;
  __shared__ float rv[256];
  __shared__ int ri[256];
  __shared__ float seld[TOPK];
  __shared__ int selj[TOPK];

  // ---- ln = ||latent_b||^2 ----
  float lsq = 0.f;
  const float4* lrow4 =
      reinterpret_cast<const float4*>(latent + (size_t)b * K_D);
  for (int f = tid; f < K_D / 4; f += 256) {
    const float4 p = lrow4[f];
    lsq += p.x * p.x + p.y * p.y + p.z * p.z + p.w * p.w;
  }
  rv[tid] = lsq;
  __syncthreads();
  for (int off = 128; off > 0; off >>= 1) {
    if (tid < off) rv[tid] += rv[tid + off];
    __syncthreads();
  }
  const float ln = rv[0];
  __syncthreads();

  // ---- d2[j] = ln + sum_kc partial[kc, j>>5][b][j&31] ----
  float d[4];
  bool used[4];
#pragma unroll
  for (int i = 0; i < 4; i++) {
    const int j = i * 256 + tid;
    float s = ln;
    const size_t off0 = (size_t)(j >> 5) * (M_B * NTILE) + b * NTILE + (j & 31);
    for (int kc = 0; kc < NKC; ++kc)
      s += partial[off0 + (size_t)kc * NNT * (M_B * NTILE)];
    d[i] = s;
    used[i] = false;
  }
  for (int it = 0; it < TOPK; ++it) {
    float best = 3.4e38f;
    int bj = N_C;
#pragma unroll
    for (int i = 0; i < 4; i++) {  // ascending j + strict < => lowest idx wins
      const int j = i * 256 + tid;
      if (!used[i] && d[i] < best) { best = d[i]; bj = j; }
    }
    rv[tid] = best;
    ri[tid] = bj;
    __syncthreads();
    for (int off = 128; off > 0; off >>= 1) {
      if (tid < off) {
        const float ov = rv[tid + off];
        const int oj = ri[tid + off];
        if (ov < rv[tid] || (ov == rv[tid] && oj < ri[tid])) {
          rv[tid] = ov;
          ri[tid] = oj;
        }
      }
      __syncthreads();
    }
    const int jw = ri[0];
    const float dw = rv[0];
    if (tid == 0) { selj[it] = jw; seld[it] = dw; }
    if ((jw & 255) == tid) used[jw >> 8] = true;  // exclude winner
    __syncthreads();
  }
  if (tid == 0) {
    float dist[TOPK], w[TOPK], wsum = 0.f;
#pragma unroll
    for (int k = 0; k < TOPK; k++) dist[k] = sqrtf(fmaxf(seld[k], 0.f));
#pragma unroll
    for (int k = 0; k < TOPK; k++) {
      w[k] = expf((dist[0] - dist[k]) / TEMP);  // stable: dist[0] is min
      wsum += w[k];
    }
#pragma unroll
    for (int k = 0; k < TOPK; k++) {
      w[k] /= wsum;
      topidx[b * TOPK + k] = selj[k];
      topw[b * TOPK + k] = w[k];
      atomicAdd(out_usage + selj[k], w[k]);
    }
    out_idx[b] = (float)selj[0];  // harness reads flat float32 buffer
    out_dist[b] = dist[0];
  }
}

// ---------------------------------------------------------------------------
// quantized[b,:] = sum_k w[b,k] * codebook[idx[b,k],:]   (float4 gather)
// NOTE: overwrites the quant region that gemm used for partials.
// ---------------------------------------------------------------------------
__global__ __launch_bounds__(256) void quantize(
    const float* __restrict__ codebook, const int* __restrict__ topidx,
    const float* __restrict__ topw, float* __restrict__ out) {
  const int b = blockIdx.y;
  const int dc = blockIdx.x;  // 8 chunks of 1000 float4 = 32000 floats
  const int tid = threadIdx.x;
  int idx[TOPK];
  float w[TOPK];
#pragma unroll
  for (int k = 0; k < TOPK; k++) {
    idx[k] = topidx[b * TOPK + k];
    w[k] = topw[b * TOPK + k];
  }
  const int f4base = dc * 1000;
#pragma unroll
  for (int s = 0; s < 4; s++) {
    const int f = tid + s * 256;
    if (f < 1000) {
      const int dpos = (f4base + f) * 4;
      float4 q = {0.f, 0.f, 0.f, 0.f};
#pragma unroll
      for (int k = 0; k < TOPK; k++) {
        const float4 c = *reinterpret_cast<const float4*>(
            codebook + (size_t)idx[k] * K_D + dpos);
        q.x += w[k] * c.x;
        q.y += w[k] * c.y;
        q.z += w[k] * c.z;
        q.w += w[k] * c.w;
      }
      *reinterpret_cast<float4*>(out + (size_t)b * K_D + dpos) = q;
    }
  }
}

// ---------------------------------------------------------------------------
extern "C" void kernel_launch(void* const* d_in, const int* in_sizes, int n_in,
                              void* d_out, int out_size, void* d_ws,
                              size_t ws_size, hipStream_t stream) {
  const float* latent = (const float*)d_in[0];    // 128*32000
  const float* codebook = (const float*)d_in[1];  // 1024*32000
  const float* usage_in = (const float*)d_in[2];  // 1024

  float* out = (float*)d_out;
  float* quant = out;                // 4,096,000 floats
  float* out_idx = out + 4096000;    // 128
  float* out_dist = out + 4096128;   // 128
  float* out_usage = out + 4096256;  // 1024

  float* ws = (float*)d_ws;
  int* topidx = (int*)(ws + WS_TOPI);
  float* topw = ws + WS_TOPW;

  // Partial scratch: 800 slots x 128x32 floats = 12.8 MB, lives in the quant
  // region (16.38 MB) — dead until quantize fully overwrites it.
  float* partial = quant;

  gemm_dist<<<dim3(NNT, NKC), 256, 0, stream>>>(latent, codebook, usage_in,
                                                out_usage, partial);
  finalize<<<128, 256, 0, stream>>>(latent, partial, out_idx, out_dist,
                                    out_usage, topidx, topw);
  quantize<<<dim3(8, 128), 256, 0, stream>>>(codebook, topidx, topw, quant);
}

// Round 5
// 284.223 us; speedup vs baseline: 1.0511x; 1.0511x over previous
//
#include <hip/hip_runtime.h>
#include <math.h>

// Problem constants
#define M_B   128      // batch
#define N_C   1024     // codes
#define K_D   32000    // feature dim (8*250*16)
#define NTILE 64       // codes per block
#define KCHUNK 320     // K per block (16 N-tiles x 100 K-chunks = 1600 blocks)
#define KSTEP 64       // bf16 elems staged in LDS per step (5 steps/block)
#define NSTAGE (KCHUNK / KSTEP)
#define LDSK  (KSTEP + 8)   // +8 bf16 pad: row stride 144B -> ~2-way banks (free)
#define TOPK  5
#define TEMP  0.1f

typedef short bf16x8 __attribute__((ext_vector_type(8)));  // 8 bf16 (4 VGPRs)
typedef float f32x4  __attribute__((ext_vector_type(4)));

// ws layout (float offsets)
#define WS_CROSS   0         // [128][1024]
#define WS_CNORM   131072    // [1024]
#define WS_ZERO_N  132096    // floats to zero (cross+cnorm)
#define WS_TOPI    132224    // [128*5] int
#define WS_TOPW    132864    // [128*5]
#define WS_LNORM16 133504    // [128][16] per-(row,block) latent-norm partials

// Barrier WITHOUT vmcnt drain: only LDS (lgkm) visibility is needed for the
// double-buffer handoff. Critically, all global loads are issued BEFORE this
// point in source order (sched_barrier(0) pins them there) and consumed a
// full step later — they stay in flight across the barrier (r1+r3 lesson).
#define LDS_BARRIER()                                        \
  do {                                                       \
    asm volatile("s_waitcnt lgkmcnt(0)" ::: "memory");       \
    __builtin_amdgcn_s_barrier();                            \
    __builtin_amdgcn_sched_barrier(0);                       \
  } while (0)

// ---------------------------------------------------------------------------
// fp32x8 -> bf16x8 hi plane + lo plane (exact split: x = hi + lo + ~2^-18 rel)
// ---------------------------------------------------------------------------
__device__ inline void cvt8(const float4 p0, const float4 p1, uint4& hi,
                            uint4& lo) {
  const unsigned int u0 = __float_as_uint(p0.x), u1 = __float_as_uint(p0.y);
  const unsigned int u2 = __float_as_uint(p0.z), u3 = __float_as_uint(p0.w);
  const unsigned int u4 = __float_as_uint(p1.x), u5 = __float_as_uint(p1.y);
  const unsigned int u6 = __float_as_uint(p1.z), u7 = __float_as_uint(p1.w);
  hi.x = (u0 >> 16) | (u1 & 0xFFFF0000u);
  hi.y = (u2 >> 16) | (u3 & 0xFFFF0000u);
  hi.z = (u4 >> 16) | (u5 & 0xFFFF0000u);
  hi.w = (u6 >> 16) | (u7 & 0xFFFF0000u);
  const float l0 = p0.x - __uint_as_float(u0 & 0xFFFF0000u);
  const float l1 = p0.y - __uint_as_float(u1 & 0xFFFF0000u);
  const float l2 = p0.z - __uint_as_float(u2 & 0xFFFF0000u);
  const float l3 = p0.w - __uint_as_float(u3 & 0xFFFF0000u);
  const float l4 = p1.x - __uint_as_float(u4 & 0xFFFF0000u);
  const float l5 = p1.y - __uint_as_float(u5 & 0xFFFF0000u);
  const float l6 = p1.z - __uint_as_float(u6 & 0xFFFF0000u);
  const float l7 = p1.w - __uint_as_float(u7 & 0xFFFF0000u);
  lo.x = (__float_as_uint(l0) >> 16) | (__float_as_uint(l1) & 0xFFFF0000u);
  lo.y = (__float_as_uint(l2) >> 16) | (__float_as_uint(l3) & 0xFFFF0000u);
  lo.z = (__float_as_uint(l4) >> 16) | (__float_as_uint(l5) & 0xFFFF0000u);
  lo.w = (__float_as_uint(l6) >> 16) | (__float_as_uint(l7) & 0xFFFF0000u);
}

__device__ inline float sq8(const float4 p0, const float4 p1) {
  return p0.x * p0.x + p0.y * p0.y + p0.z * p0.z + p0.w * p0.w +
         p1.x * p1.x + p1.y * p1.y + p1.z * p1.z + p1.w * p1.w;
}

// ---------------------------------------------------------------------------
// prep (merged): bx<16  -> convert latent row `by` into Ah/Al bf16 planes
//                         (stored in out's quant region — dead until quantize
//                         overwrites it) + lnorm16 partials (no atomics).
//                bx==16 -> zero cross/cnorm + copy usage.
// ---------------------------------------------------------------------------
__global__ __launch_bounds__(256) void prep(
    const float* __restrict__ latent, const float* __restrict__ usage_in,
    float* __restrict__ ws, float* __restrict__ usage_out,
    unsigned short* __restrict__ aplanes) {
  const int tid = threadIdx.x;
  const int bx = blockIdx.x;
  const int by = blockIdx.y;  // latent row 0..127
  if (bx == 16) {             // chores
    const int id2 = by * 256 + tid;
#pragma unroll
    for (int j = 0; j < 5; ++j) {
      const int idx = id2 + j * 32768;
      if (idx < WS_ZERO_N) ws[idx] = 0.f;
    }
    if (id2 < N_C) usage_out[id2] = usage_in[id2];
    return;
  }
  // ---- cvt: 4000 units of 8 floats per row; block bx covers 256 units ----
  const int u = bx * 256 + tid;
  float lsq = 0.f;
  if (u < 4000) {
    const int k = u * 8;
    const float* src = latent + (size_t)by * K_D + k;
    const float4 p0 = *reinterpret_cast<const float4*>(src);
    const float4 p1 = *reinterpret_cast<const float4*>(src + 4);
    uint4 hi, lo;
    cvt8(p0, p1, hi, lo);
    unsigned short* ah = aplanes + (size_t)by * K_D + k;
    *reinterpret_cast<uint4*>(ah) = hi;
    *reinterpret_cast<uint4*>(ah + (size_t)M_B * K_D) = lo;
    lsq = sq8(p0, p1);
  }
  // wave reduce (all lanes same row; inactive lanes carry 0)
  lsq += __shfl_down(lsq, 32);
  lsq += __shfl_down(lsq, 16);
  lsq += __shfl_down(lsq, 8);
  lsq += __shfl_down(lsq, 4);
  lsq += __shfl_down(lsq, 2);
  lsq += __shfl_down(lsq, 1);
  __shared__ float wpart[4];
  if ((tid & 63) == 0) wpart[tid >> 6] = lsq;
  __syncthreads();
  if (tid == 0)
    (ws + WS_LNORM16)[by * 16 + bx] =
        wpart[0] + wpart[1] + wpart[2] + wpart[3];
}

// ---------------------------------------------------------------------------
// Split-bf16 MFMA distance GEMM v6 — synthesis of proven pieces:
//  r1 skeleton (64-wide N tile, 1600 blocks, dbuf LDS, one barrier/step,
//  loads issued BEFORE the barrier) + r3's lgkm-only barrier (so those loads
//  SURVIVE the barrier) + r2's precomputed A planes (no A-cvt VALU in loop).
//  Steady-state step:
//    MFMA(LDS[p], A(s))          // A(s), B(s+1) issued a full step ago
//    issue A(s+1)                // bf16 frags, L2/L3-hot
//    cvt+write B(s+1) -> LDS[p^1]
//    issue B(s+2)
//    LDS_BARRIER (lgkm only)     // 12 loads stay in flight across it
//  => zero steady-state load exposure; ~4 blocks/CU residency.
// ---------------------------------------------------------------------------
__global__ __launch_bounds__(256, 4) void gemm_dist(
    const unsigned short* __restrict__ aplanes,
    const float* __restrict__ codebook, float* __restrict__ cross,
    float* __restrict__ cnorm) {
  __shared__ alignas(16) unsigned short Bh[2][NTILE][LDSK];
  __shared__ alignas(16) unsigned short Bl[2][NTILE][LDSK];

  const int tid  = threadIdx.x;
  const int nt   = blockIdx.x;   // 0..15 N tile
  const int kc   = blockIdx.y;   // 0..99 K chunk
  const int wave = tid >> 6;     // 0..3: M rows [32w, 32w+32)
  const int lane = tid & 63;
  const int lrow = lane & 15;    // MFMA fragment row/col index
  const int quad = lane >> 4;    // MFMA k-quad

  const int brow = tid >> 2;        // staging: B row 0..63
  const int bcol = (tid & 3) * 16;  // 16 k-elems (2 float4) per thread

  f32x4 acc[2][4];
#pragma unroll
  for (int mt = 0; mt < 2; ++mt)
#pragma unroll
    for (int n = 0; n < 4; ++n) {
      acc[mt][n][0] = 0.f; acc[mt][n][1] = 0.f;
      acc[mt][n][2] = 0.f; acc[mt][n][3] = 0.f;
    }
  float csq = 0.f;

  const int kbase = kc * KCHUNK;
  const float* browp = codebook + (size_t)(nt * NTILE + brow) * K_D;
  const unsigned short* al_base = aplanes + (size_t)M_B * K_D;
  const size_t arow_off = (size_t)(wave * 32 + lrow) * K_D + quad * 8;

  // ---- prologue: stage B(0) into LDS[0] (one-time exposed latency) ----
#pragma unroll
  for (int u = 0; u < 2; ++u) {
    const int kk = kbase + bcol + u * 8;
    const float4 p0 = *reinterpret_cast<const float4*>(browp + kk);
    const float4 p1 = *reinterpret_cast<const float4*>(browp + kk + 4);
    uint4 hi, lo;
    cvt8(p0, p1, hi, lo);
    *reinterpret_cast<uint4*>(&Bh[0][brow][bcol + u * 8]) = hi;
    *reinterpret_cast<uint4*>(&Bl[0][brow][bcol + u * 8]) = lo;
    csq += sq8(p0, p1);
  }
  // ---- issue A(0) fragments (bf16 planes) ----
  bf16x8 ah[2][2], al[2][2];
#pragma unroll
  for (int mt = 0; mt < 2; ++mt) {
    const size_t ro = arow_off + (size_t)mt * 16 * K_D + kbase;
#pragma unroll
    for (int kh = 0; kh < 2; ++kh) {
      ah[mt][kh] = *reinterpret_cast<const bf16x8*>(aplanes + ro + kh * 32);
      al[mt][kh] = *reinterpret_cast<const bf16x8*>(al_base + ro + kh * 32);
    }
  }
  // ---- issue B(1) ----
  float4 bp[2][2];
#pragma unroll
  for (int u = 0; u < 2; ++u) {
    const int kn = kbase + KSTEP + bcol + u * 8;
    bp[u][0] = *reinterpret_cast<const float4*>(browp + kn);
    bp[u][1] = *reinterpret_cast<const float4*>(browp + kn + 4);
  }
  LDS_BARRIER();  // LDS[0] visible; A(0)/B(1) stay in flight (lgkm-only)

#pragma unroll
  for (int s = 0; s < NSTAGE; ++s) {
    const int p = s & 1;  // compile-time after unroll
    // ---- MFMA on LDS[p] with A(s) (counted vmcnt: loads are step-old) ----
#pragma unroll
    for (int kh = 0; kh < 2; ++kh) {
      const int kf = kh * 32 + quad * 8;
#pragma unroll
      for (int n = 0; n < 4; ++n) {
        const bf16x8 bh =
            *reinterpret_cast<const bf16x8*>(&Bh[p][n * 16 + lrow][kf]);
        const bf16x8 bl =
            *reinterpret_cast<const bf16x8*>(&Bl[p][n * 16 + lrow][kf]);
#pragma unroll
        for (int mt = 0; mt < 2; ++mt) {
          acc[mt][n] = __builtin_amdgcn_mfma_f32_16x16x32_bf16(
              ah[mt][kh], bh, acc[mt][n], 0, 0, 0);
          acc[mt][n] = __builtin_amdgcn_mfma_f32_16x16x32_bf16(
              ah[mt][kh], bl, acc[mt][n], 0, 0, 0);
          acc[mt][n] = __builtin_amdgcn_mfma_f32_16x16x32_bf16(
              al[mt][kh], bh, acc[mt][n], 0, 0, 0);
        }
      }
    }
    // ---- issue A(s+1) (covered by write-phase + barrier before use) ----
    if (s + 1 < NSTAGE) {
      const int k1 = kbase + (s + 1) * KSTEP;
#pragma unroll
      for (int mt = 0; mt < 2; ++mt) {
        const size_t ro = arow_off + (size_t)mt * 16 * K_D + k1;
#pragma unroll
        for (int kh = 0; kh < 2; ++kh) {
          ah[mt][kh] =
              *reinterpret_cast<const bf16x8*>(aplanes + ro + kh * 32);
          al[mt][kh] =
              *reinterpret_cast<const bf16x8*>(al_base + ro + kh * 32);
        }
      }
    }
    // ---- cvt+write B(s+1) (loaded a full step ago -> retired) ----
    if (s + 1 < NSTAGE) {
#pragma unroll
      for (int u = 0; u < 2; ++u) {
        uint4 hi, lo;
        cvt8(bp[u][0], bp[u][1], hi, lo);
        *reinterpret_cast<uint4*>(&Bh[p ^ 1][brow][bcol + u * 8]) = hi;
        *reinterpret_cast<uint4*>(&Bl[p ^ 1][brow][bcol + u * 8]) = lo;
        csq += sq8(bp[u][0], bp[u][1]);
      }
    }
    // ---- issue B(s+2) ----
    if (s + 2 < NSTAGE) {
#pragma unroll
      for (int u = 0; u < 2; ++u) {
        const int kn = kbase + (s + 2) * KSTEP + bcol + u * 8;
        bp[u][0] = *reinterpret_cast<const float4*>(browp + kn);
        bp[u][1] = *reinterpret_cast<const float4*>(browp + kn + 4);
      }
    }
    if (s + 1 < NSTAGE) LDS_BARRIER();  // lgkm-only: 12 loads live on
  }

  // ---- split-K accumulate: C/D layout col=lane&15, row=quad*4+reg (m89) ----
#pragma unroll
  for (int mt = 0; mt < 2; ++mt) {
    const int mrow0 = wave * 32 + mt * 16 + quad * 4;
#pragma unroll
    for (int n = 0; n < 4; ++n) {
      const int col = nt * NTILE + n * 16 + lrow;
#pragma unroll
      for (int r = 0; r < 4; ++r)
        atomicAdd(cross + (size_t)(mrow0 + r) * N_C + col, acc[mt][n][r]);
    }
  }

  // ---- codebook norms: 4 threads (tid&3) share row brow ----
  csq += __shfl_down(csq, 2, 4);
  csq += __shfl_down(csq, 1, 4);
  if ((tid & 3) == 0) atomicAdd(cnorm + nt * NTILE + brow, csq);
}

// ---------------------------------------------------------------------------
// Per-latent finalize: d2 -> top-5 (lowest-index tie-break) -> softmax ->
// outputs + usage scatter + ws stash for the quantize gather.
// ---------------------------------------------------------------------------
__global__ __launch_bounds__(256) void finalize(
    const float* __restrict__ cross, const float* __restrict__ cnorm,
    const float* __restrict__ lnorm16, float* __restrict__ out_idx,
    float* __restrict__ out_dist, float* __restrict__ out_usage,
    int* __restrict__ topidx, float* __restrict__ topw) {
  const int b = blockIdx.x;
  const int tid = threadIdx.x;
  __shared__ float rv[256];
  __shared__ int ri[256];
  __shared__ float seld[TOPK];
  __shared__ int selj[TOPK];

  float ln = 0.f;
#pragma unroll
  for (int x = 0; x < 16; ++x) ln += lnorm16[b * 16 + x];

  float d[4];
  bool used[4];
#pragma unroll
  for (int i = 0; i < 4; i++) {
    const int j = i * 256 + tid;
    d[i] = ln + cnorm[j] - 2.f * cross[b * N_C + j];
    used[i] = false;
  }
  for (int it = 0; it < TOPK; ++it) {
    float best = 3.4e38f;
    int bj = N_C;
#pragma unroll
    for (int i = 0; i < 4; i++) {  // ascending j + strict < => lowest idx wins
      const int j = i * 256 + tid;
      if (!used[i] && d[i] < best) { best = d[i]; bj = j; }
    }
    rv[tid] = best;
    ri[tid] = bj;
    __syncthreads();
    for (int off = 128; off > 0; off >>= 1) {
      if (tid < off) {
        const float ov = rv[tid + off];
        const int oj = ri[tid + off];
        if (ov < rv[tid] || (ov == rv[tid] && oj < ri[tid])) {
          rv[tid] = ov;
          ri[tid] = oj;
        }
      }
      __syncthreads();
    }
    const int jw = ri[0];
    const float dw = rv[0];
    if (tid == 0) { selj[it] = jw; seld[it] = dw; }
    if ((jw & 255) == tid) used[jw >> 8] = true;  // exclude winner
    __syncthreads();
  }
  if (tid == 0) {
    float dist[TOPK], w[TOPK], wsum = 0.f;
#pragma unroll
    for (int k = 0; k < TOPK; k++) dist[k] = sqrtf(fmaxf(seld[k], 0.f));
#pragma unroll
    for (int k = 0; k < TOPK; k++) {
      w[k] = expf((dist[0] - dist[k]) / TEMP);  // stable: dist[0] is min
      wsum += w[k];
    }
#pragma unroll
    for (int k = 0; k < TOPK; k++) {
      w[k] /= wsum;
      topidx[b * TOPK + k] = selj[k];
      topw[b * TOPK + k] = w[k];
      atomicAdd(out_usage + selj[k], w[k]);
    }
    out_idx[b] = (float)selj[0];  // harness reads flat float32 buffer
    out_dist[b] = dist[0];
  }
}

// ---------------------------------------------------------------------------
// quantized[b,:] = sum_k w[b,k] * codebook[idx[b,k],:]   (float4 gather)
// NOTE: overwrites the quant region that prep used as A-plane scratch.
// ---------------------------------------------------------------------------
__global__ __launch_bounds__(256) void quantize(
    const float* __restrict__ codebook, const int* __restrict__ topidx,
    const float* __restrict__ topw, float* __restrict__ out) {
  const int b = blockIdx.y;
  const int dc = blockIdx.x;  // 8 chunks of 1000 float4 = 32000 floats
  const int tid = threadIdx.x;
  int idx[TOPK];
  float w[TOPK];
#pragma unroll
  for (int k = 0; k < TOPK; k++) {
    idx[k] = topidx[b * TOPK + k];
    w[k] = topw[b * TOPK + k];
  }
  const int f4base = dc * 1000;
#pragma unroll
  for (int s = 0; s < 4; s++) {
    const int f = tid + s * 256;
    if (f < 1000) {
      const int dpos = (f4base + f) * 4;
      float4 q = {0.f, 0.f, 0.f, 0.f};
#pragma unroll
      for (int k = 0; k < TOPK; k++) {
        const float4 c = *reinterpret_cast<const float4*>(
            codebook + (size_t)idx[k] * K_D + dpos);
        q.x += w[k] * c.x;
        q.y += w[k] * c.y;
        q.z += w[k] * c.z;
        q.w += w[k] * c.w;
      }
      *reinterpret_cast<float4*>(out + (size_t)b * K_D + dpos) = q;
    }
  }
}

// ---------------------------------------------------------------------------
extern "C" void kernel_launch(void* const* d_in, const int* in_sizes, int n_in,
                              void* d_out, int out_size, void* d_ws,
                              size_t ws_size, hipStream_t stream) {
  const float* latent = (const float*)d_in[0];    // 128*32000
  const float* codebook = (const float*)d_in[1];  // 1024*32000
  const float* usage_in = (const float*)d_in[2];  // 1024

  float* out = (float*)d_out;
  float* quant = out;                // 4,096,000 floats
  float* out_idx = out + 4096000;    // 128
  float* out_dist = out + 4096128;   // 128
  float* out_usage = out + 4096256;  // 1024

  float* ws = (float*)d_ws;
  float* cross = ws + WS_CROSS;
  float* cnorm = ws + WS_CNORM;
  float* lnorm16 = ws + WS_LNORM16;
  int* topidx = (int*)(ws + WS_TOPI);
  float* topw = ws + WS_TOPW;

  // A-plane scratch: quant region is exactly 16,384,000 B = Ah+Al planes,
  // dead until quantize fully overwrites it.
  unsigned short* aplanes = (unsigned short*)quant;

  prep<<<dim3(17, 128), 256, 0, stream>>>(latent, usage_in, ws, out_usage,
                                          aplanes);
  gemm_dist<<<dim3(16, 100), 256, 0, stream>>>(aplanes, codebook, cross,
                                               cnorm);
  finalize<<<128, 256, 0, stream>>>(cross, cnorm, lnorm16, out_idx, out_dist,
                                    out_usage, topidx, topw);
  quantize<<<dim3(8, 128), 256, 0, stream>>>(codebook, topidx, topw, quant);
}

// Round 6
// 268.738 us; speedup vs baseline: 1.1116x; 1.0576x over previous
//
#include <hip/hip_runtime.h>
#include <math.h>

// Problem constants
#define M_B   128      // batch
#define N_C   1024     // codes
#define K_D   32000    // feature dim (8*250*16)
#define NTILE 64       // codes per block
#define KCHUNK 640     // K per block (16 N-tiles x 50 K-chunks = 800 blocks)
#define KSTEP 64       // fp32 elems staged per step (10 steps/block)
#define NSTAGE (KCHUNK / KSTEP)  // 10
#define NBUF  4        // LDS ring depth (3 tiles in flight)
#define TOPK  5
#define TEMP  0.1f

typedef short bf16x8 __attribute__((ext_vector_type(8)));  // 8 bf16 (4 VGPRs)
typedef float f32x4  __attribute__((ext_vector_type(4)));

// ws layout (float offsets)
#define WS_CROSS   0         // [128][1024]
#define WS_CNORM   131072    // [1024]
#define WS_LNORM   132096    // [128]
#define WS_TOPI    132224    // [128*5] int
#define WS_TOPW    132864    // [128*5]
#define WS_ZERO_N  132224    // floats to zero (cross+cnorm+lnorm)

// HBM -> LDS DMA, 16 B per lane, no VGPR round-trip. In-flight depth costs
// nothing in registers — this is what finally fixes the Little's-law cap.
#define GLOAD16(g, l)                                            \
  __builtin_amdgcn_global_load_lds(                              \
      (const __attribute__((address_space(1))) void*)(g),        \
      (__attribute__((address_space(3))) void*)(l), 16, 0, 0)

// Barrier WITHOUT vmcnt drain (lgkm only): DMA'd prefetches live across it.
#define LDS_BARRIER()                                        \
  do {                                                       \
    asm volatile("s_waitcnt lgkmcnt(0)" ::: "memory");       \
    __builtin_amdgcn_s_barrier();                            \
    __builtin_amdgcn_sched_barrier(0);                       \
  } while (0)

// ---------------------------------------------------------------------------
// fp32x8 -> bf16x8 hi plane + lo plane (exact split: x = hi + lo + ~2^-18 rel)
// ---------------------------------------------------------------------------
__device__ inline void cvt8(const float4 p0, const float4 p1, uint4& hi,
                            uint4& lo) {
  const unsigned int u0 = __float_as_uint(p0.x), u1 = __float_as_uint(p0.y);
  const unsigned int u2 = __float_as_uint(p0.z), u3 = __float_as_uint(p0.w);
  const unsigned int u4 = __float_as_uint(p1.x), u5 = __float_as_uint(p1.y);
  const unsigned int u6 = __float_as_uint(p1.z), u7 = __float_as_uint(p1.w);
  hi.x = (u0 >> 16) | (u1 & 0xFFFF0000u);
  hi.y = (u2 >> 16) | (u3 & 0xFFFF0000u);
  hi.z = (u4 >> 16) | (u5 & 0xFFFF0000u);
  hi.w = (u6 >> 16) | (u7 & 0xFFFF0000u);
  const float l0 = p0.x - __uint_as_float(u0 & 0xFFFF0000u);
  const float l1 = p0.y - __uint_as_float(u1 & 0xFFFF0000u);
  const float l2 = p0.z - __uint_as_float(u2 & 0xFFFF0000u);
  const float l3 = p0.w - __uint_as_float(u3 & 0xFFFF0000u);
  const float l4 = p1.x - __uint_as_float(u4 & 0xFFFF0000u);
  const float l5 = p1.y - __uint_as_float(u5 & 0xFFFF0000u);
  const float l6 = p1.z - __uint_as_float(u6 & 0xFFFF0000u);
  const float l7 = p1.w - __uint_as_float(u7 & 0xFFFF0000u);
  lo.x = (__float_as_uint(l0) >> 16) | (__float_as_uint(l1) & 0xFFFF0000u);
  lo.y = (__float_as_uint(l2) >> 16) | (__float_as_uint(l3) & 0xFFFF0000u);
  lo.z = (__float_as_uint(l4) >> 16) | (__float_as_uint(l5) & 0xFFFF0000u);
  lo.w = (__float_as_uint(l6) >> 16) | (__float_as_uint(l7) & 0xFFFF0000u);
}

__device__ inline float sq8(const float4 p0, const float4 p1) {
  return p0.x * p0.x + p0.y * p0.y + p0.z * p0.z + p0.w * p0.w +
         p1.x * p1.x + p1.y * p1.y + p1.z * p1.z + p1.w * p1.w;
}

// ---------------------------------------------------------------------------
// prep (chores only): zero cross/cnorm/lnorm + copy usage.
// ---------------------------------------------------------------------------
__global__ void prep(float* __restrict__ ws, const float* __restrict__ usage_in,
                     float* __restrict__ usage_out) {
  const int i = blockIdx.x * 256 + threadIdx.x;
  if (i < WS_ZERO_N) ws[i] = 0.f;
  if (i < N_C) usage_out[i] = usage_in[i];
}

// ---------------------------------------------------------------------------
// Split-bf16 MFMA distance GEMM v7 — DMA-ring pipeline.
//  Diagnosis r0-r5 (Little's law): register-staged B caps in-flight bytes at
//  ~200 B/wave -> ~2.2 TB/s, matching every measured round. Fix: stage raw
//  fp32 B via global_load_lds into a 4-buffer LDS ring; ~3 tiles (48 KB) in
//  flight per block continuously, VGPR-free.
//  Per step s:  cvt A(s) [compiler vmcnt drains g(s+1) by FIFO order]
//               issue A(s+1); DMA-stage g(s+3) -> buf[(s+3)&3]
//               MFMA phase: swizzled ds_read fp32 -> cvt -> 3-plane MFMA
//               lgkm-only barrier (publishes buf(s+1); DMA stays in flight)
//  LDS reads bank-spread via XOR swizzle applied on BOTH sides (rule #21):
//  inverse-swizzled global source addr (DMA writes linear) + swizzled read.
// ---------------------------------------------------------------------------
__global__ __launch_bounds__(256, 2) void gemm_dist(
    const float* __restrict__ latent, const float* __restrict__ codebook,
    float* __restrict__ cross, float* __restrict__ cnorm,
    float* __restrict__ lnorm) {
  __shared__ float buf[NBUF][NTILE * KSTEP];  // 4 x 16 KB, linear for DMA

  const int tid  = threadIdx.x;
  const int nt   = blockIdx.x;   // 0..15 N tile
  const int kc   = blockIdx.y;   // 0..49 K chunk
  const int wave = tid >> 6;     // 0..3: M rows [32w, 32w+32)
  const int lane = tid & 63;
  const int lrow = lane & 15;    // MFMA fragment row/col index
  const int quad = lane >> 4;    // MFMA k-quad
  const int kbase = kc * KCHUNK;

  // ---- staging geometry: wave w covers B rows [16w,16w+16), instr i rows
  // +4i; lane l -> row +(l>>4), LDS floats lane*4. Source col is
  // inverse-XOR-swizzled: global col = ((l&15) ^ (row&7)) * 4.
  size_t gofs[4];
  int lofs[4];
#pragma unroll
  for (int i = 0; i < 4; ++i) {
    const int row = wave * 16 + i * 4 + (lane >> 4);
    gofs[i] =
        (size_t)(nt * NTILE + row) * K_D + (((lane & 15) ^ (row & 7)) << 2);
    lofs[i] = wave * 1024 + i * 256 + lane * 4;
  }

  f32x4 acc[2][4];
#pragma unroll
  for (int mt = 0; mt < 2; ++mt)
#pragma unroll
    for (int n = 0; n < 4; ++n) {
      acc[mt][n][0] = 0.f; acc[mt][n][1] = 0.f;
      acc[mt][n][2] = 0.f; acc[mt][n][3] = 0.f;
    }
  float csqn[4] = {0.f, 0.f, 0.f, 0.f};
  float lsq[2] = {0.f, 0.f};

  const size_t arow0 = (size_t)(wave * 32 + lrow) * K_D + quad * 8;
  float4 ap[2][2][2];  // A(s) fp32 in flight [mt][kh][half]

  // ---- prologue: issue A(0); DMA buffers 0,1,2; wait g(0)+A(0) ----
#pragma unroll
  for (int mt = 0; mt < 2; ++mt) {
    const float* ar = latent + arow0 + (size_t)mt * 16 * K_D + kbase;
#pragma unroll
    for (int kh = 0; kh < 2; ++kh) {
      ap[mt][kh][0] = *reinterpret_cast<const float4*>(ar + kh * 32);
      ap[mt][kh][1] = *reinterpret_cast<const float4*>(ar + kh * 32 + 4);
    }
  }
#pragma unroll
  for (int b = 0; b < 3; ++b)
#pragma unroll
    for (int i = 0; i < 4; ++i)
      GLOAD16(codebook + gofs[i] + kbase + b * KSTEP, &buf[b][lofs[i]]);
  asm volatile("s_waitcnt vmcnt(8)" ::: "memory");  // A(0)+g(0) done; g1,g2 fly
  __builtin_amdgcn_s_barrier();
  __builtin_amdgcn_sched_barrier(0);

#pragma unroll
  for (int s = 0; s < NSTAGE; ++s) {
    const float* bufr = buf[s & 3];
    // ---- cvt A(s): compiler's counted vmcnt also drains g(s+1) (FIFO) ----
    bf16x8 ah[2][2], al[2][2];
#pragma unroll
    for (int mt = 0; mt < 2; ++mt)
#pragma unroll
      for (int kh = 0; kh < 2; ++kh) {
        uint4 hi, lo;
        cvt8(ap[mt][kh][0], ap[mt][kh][1], hi, lo);
        ah[mt][kh] = *reinterpret_cast<bf16x8*>(&hi);
        al[mt][kh] = *reinterpret_cast<bf16x8*>(&lo);
        if (nt == 0) lsq[mt] += sq8(ap[mt][kh][0], ap[mt][kh][1]);
      }
    // ---- issue A(s+1) (L3-hot; consumed next step) ----
    if (s + 1 < NSTAGE) {
#pragma unroll
      for (int mt = 0; mt < 2; ++mt) {
        const float* ar = latent + arow0 + (size_t)mt * 16 * K_D + kbase +
                          (s + 1) * KSTEP;
#pragma unroll
        for (int kh = 0; kh < 2; ++kh) {
          ap[mt][kh][0] = *reinterpret_cast<const float4*>(ar + kh * 32);
          ap[mt][kh][1] = *reinterpret_cast<const float4*>(ar + kh * 32 + 4);
        }
      }
    }
    // ---- DMA-stage buf for step s+3 (slot read-retired at step s-1) ----
    if (s + 3 < NSTAGE) {
#pragma unroll
      for (int i = 0; i < 4; ++i)
        GLOAD16(codebook + gofs[i] + kbase + (s + 3) * KSTEP,
                &buf[(s + 3) & 3][lofs[i]]);
    }
    // ---- MFMA: swizzled fp32 reads -> cvt -> 3-plane bf16 MFMA ----
#pragma unroll
    for (int kh = 0; kh < 2; ++kh) {
#pragma unroll
      for (int n = 0; n < 4; ++n) {
        const int row = n * 16 + lrow;
        const int fb = row * 64 + kh * 32 +
                       ((quad ^ ((row >> 1) & 3)) << 3) + ((row & 1) << 2);
        const float4 f0 = *reinterpret_cast<const float4*>(&bufr[fb]);
        const float4 f1 = *reinterpret_cast<const float4*>(&bufr[fb ^ 4]);
        uint4 hi, lo;
        cvt8(f0, f1, hi, lo);
        const bf16x8 bh = *reinterpret_cast<bf16x8*>(&hi);
        const bf16x8 bl = *reinterpret_cast<bf16x8*>(&lo);
        if (wave == 0) csqn[n] += sq8(f0, f1);  // wave0 tiles B exactly once
#pragma unroll
        for (int mt = 0; mt < 2; ++mt) {
          acc[mt][n] = __builtin_amdgcn_mfma_f32_16x16x32_bf16(
              ah[mt][kh], bh, acc[mt][n], 0, 0, 0);
          acc[mt][n] = __builtin_amdgcn_mfma_f32_16x16x32_bf16(
              ah[mt][kh], bl, acc[mt][n], 0, 0, 0);
          acc[mt][n] = __builtin_amdgcn_mfma_f32_16x16x32_bf16(
              al[mt][kh], bh, acc[mt][n], 0, 0, 0);
        }
      }
    }
    if (s + 1 < NSTAGE) LDS_BARRIER();  // lgkm-only: DMA stays in flight
  }

  // ---- split-K accumulate: C/D layout col=lane&15, row=quad*4+reg (m89) ----
#pragma unroll
  for (int mt = 0; mt < 2; ++mt) {
    const int mrow0 = wave * 32 + mt * 16 + quad * 4;
#pragma unroll
    for (int n = 0; n < 4; ++n) {
      const int col = nt * NTILE + n * 16 + lrow;
#pragma unroll
      for (int r = 0; r < 4; ++r)
        atomicAdd(cross + (size_t)(mrow0 + r) * N_C + col, acc[mt][n][r]);
    }
  }
  // ---- codebook norms (wave 0): reduce over quads ----
  if (wave == 0) {
#pragma unroll
    for (int n = 0; n < 4; ++n) {
      float c = csqn[n];
      c += __shfl_down(c, 32);
      c += __shfl_down(c, 16);
      if (lane < 16) atomicAdd(cnorm + nt * NTILE + n * 16 + lane, c);
    }
  }
  // ---- latent norms (nt==0 blocks cover all K): reduce over quads ----
  if (nt == 0) {
#pragma unroll
    for (int mt = 0; mt < 2; ++mt) {
      float v = lsq[mt];
      v += __shfl_down(v, 32);
      v += __shfl_down(v, 16);
      if (lane < 16) atomicAdd(lnorm + wave * 32 + mt * 16 + lane, v);
    }
  }
}

// ---------------------------------------------------------------------------
// Per-latent finalize: d2 -> top-5 (lowest-index tie-break) -> softmax ->
// outputs + usage scatter + ws stash for the quantize gather.
// ---------------------------------------------------------------------------
__global__ __launch_bounds__(256) void finalize(
    const float* __restrict__ cross, const float* __restrict__ cnorm,
    const float* __restrict__ lnorm, float* __restrict__ out_idx,
    float* __restrict__ out_dist, float* __restrict__ out_usage,
    int* __restrict__ topidx, float* __restrict__ topw) {
  const int b = blockIdx.x;
  const int tid = threadIdx.x;
  __shared__ float rv[256];
  __shared__ int ri[256];
  __shared__ float seld[TOPK];
  __shared__ int selj[TOPK];

  float d[4];
  bool used[4];
  const float ln = lnorm[b];
#pragma unroll
  for (int i = 0; i < 4; i++) {
    const int j = i * 256 + tid;
    d[i] = ln + cnorm[j] - 2.f * cross[b * N_C + j];
    used[i] = false;
  }
  for (int it = 0; it < TOPK; ++it) {
    float best = 3.4e38f;
    int bj = N_C;
#pragma unroll
    for (int i = 0; i < 4; i++) {  // ascending j + strict < => lowest idx wins
      const int j = i * 256 + tid;
      if (!used[i] && d[i] < best) { best = d[i]; bj = j; }
    }
    rv[tid] = best;
    ri[tid] = bj;
    __syncthreads();
    for (int off = 128; off > 0; off >>= 1) {
      if (tid < off) {
        const float ov = rv[tid + off];
        const int oj = ri[tid + off];
        if (ov < rv[tid] || (ov == rv[tid] && oj < ri[tid])) {
          rv[tid] = ov;
          ri[tid] = oj;
        }
      }
      __syncthreads();
    }
    const int jw = ri[0];
    const float dw = rv[0];
    if (tid == 0) { selj[it] = jw; seld[it] = dw; }
    if ((jw & 255) == tid) used[jw >> 8] = true;  // exclude winner
    __syncthreads();
  }
  if (tid == 0) {
    float dist[TOPK], w[TOPK], wsum = 0.f;
#pragma unroll
    for (int k = 0; k < TOPK; k++) dist[k] = sqrtf(fmaxf(seld[k], 0.f));
#pragma unroll
    for (int k = 0; k < TOPK; k++) {
      w[k] = expf((dist[0] - dist[k]) / TEMP);  // stable: dist[0] is min
      wsum += w[k];
    }
#pragma unroll
    for (int k = 0; k < TOPK; k++) {
      w[k] /= wsum;
      topidx[b * TOPK + k] = selj[k];
      topw[b * TOPK + k] = w[k];
      atomicAdd(out_usage + selj[k], w[k]);
    }
    out_idx[b] = (float)selj[0];  // harness reads flat float32 buffer
    out_dist[b] = dist[0];
  }
}

// ---------------------------------------------------------------------------
// quantized[b,:] = sum_k w[b,k] * codebook[idx[b,k],:]   (float4 gather)
// ---------------------------------------------------------------------------
__global__ __launch_bounds__(256) void quantize(
    const float* __restrict__ codebook, const int* __restrict__ topidx,
    const float* __restrict__ topw, float* __restrict__ out) {
  const int b = blockIdx.y;
  const int dc = blockIdx.x;  // 8 chunks of 1000 float4 = 32000 floats
  const int tid = threadIdx.x;
  int idx[TOPK];
  float w[TOPK];
#pragma unroll
  for (int k = 0; k < TOPK; k++) {
    idx[k] = topidx[b * TOPK + k];
    w[k] = topw[b * TOPK + k];
  }
  const int f4base = dc * 1000;
#pragma unroll
  for (int s = 0; s < 4; s++) {
    const int f = tid + s * 256;
    if (f < 1000) {
      const int dpos = (f4base + f) * 4;
      float4 q = {0.f, 0.f, 0.f, 0.f};
#pragma unroll
      for (int k = 0; k < TOPK; k++) {
        const float4 c = *reinterpret_cast<const float4*>(
            codebook + (size_t)idx[k] * K_D + dpos);
        q.x += w[k] * c.x;
        q.y += w[k] * c.y;
        q.z += w[k] * c.z;
        q.w += w[k] * c.w;
      }
      *reinterpret_cast<float4*>(out + (size_t)b * K_D + dpos) = q;
    }
  }
}

// ---------------------------------------------------------------------------
extern "C" void kernel_launch(void* const* d_in, const int* in_sizes, int n_in,
                              void* d_out, int out_size, void* d_ws,
                              size_t ws_size, hipStream_t stream) {
  const float* latent = (const float*)d_in[0];    // 128*32000
  const float* codebook = (const float*)d_in[1];  // 1024*32000
  const float* usage_in = (const float*)d_in[2];  // 1024

  float* out = (float*)d_out;
  float* quant = out;                // 4,096,000
  float* out_idx = out + 4096000;    // 128
  float* out_dist = out + 4096128;   // 128
  float* out_usage = out + 4096256;  // 1024

  float* ws = (float*)d_ws;
  float* cross = ws + WS_CROSS;
  float* cnorm = ws + WS_CNORM;
  float* lnorm = ws + WS_LNORM;
  int* topidx = (int*)(ws + WS_TOPI);
  float* topw = ws + WS_TOPW;

  prep<<<(WS_ZERO_N + 255) / 256, 256, 0, stream>>>(ws, usage_in, out_usage);
  gemm_dist<<<dim3(16, 50), 256, 0, stream>>>(latent, codebook, cross, cnorm,
                                              lnorm);
  finalize<<<128, 256, 0, stream>>>(cross, cnorm, lnorm, out_idx, out_dist,
                                    out_usage, topidx, topw);
  quantize<<<dim3(8, 128), 256, 0, stream>>>(codebook, topidx, topw, quant);
}